// Round 4
// baseline (498.150 us; speedup 1.0000x reference)
//
#include <hip/hip_runtime.h>
#include <math.h>

// ---------------------------------------------------------------------------
// 3-layer GCN + softmax on MI355X, fp32 end-to-end.
// A(XW) = (AX)W -> aggregate first (F=6 for layer 1).
// R3: two-level bucket sort builds a node-ordered CSR with sequential writes
//     (replaces the random-64B-granule ELL scatter that wrote 102 MB);
//     k_build fuses deg/dis/x-prescale; agg64 uses 8 lanes/node (8 gather
//     streams per wave). Pre-scaled activations h' = dis*h fold dis[src]
//     into dense epilogues.
// ---------------------------------------------------------------------------

#define BLK 256
#define KB  512            // buckets
#define BNMAX 128          // max nodes per bucket (N=50000/512 -> 98)

// ---- pass 0: bucket histogram (counters padded to one line each) -----------

__global__ void k_bcount(const int* __restrict__ col, int E, int BN,
                         int* __restrict__ bcnt) {
  int e = blockIdx.x * blockDim.x + threadIdx.x;
  if (e >= E) return;
  atomicAdd(&bcnt[(col[e] / BN) << 4], 1);
}

// ---- pass 0.5: exclusive scan of bucket counts; also init softmax cell -----

__global__ void k_bscan(const int* __restrict__ bcnt, int* __restrict__ bbase,
                        float* __restrict__ red, int K) {
  __shared__ int s[KB + 1];
  int t = threadIdx.x;
  for (int i = t; i < K; i += blockDim.x) s[i] = bcnt[i << 4];
  __syncthreads();
  if (t == 0) {
    int run = 0;
    for (int i = 0; i < K; ++i) { int c = s[i]; s[i] = run; run += c; }
    s[K] = run;
    red[0] = -3.0e38f; red[1] = 0.0f;
  }
  __syncthreads();
  for (int i = t; i <= K; i += blockDim.x) bbase[i] = s[i];
}

// ---- pass A: scatter edges into contiguous bucket regions ------------------
// Packed entry: .x = row | (local_col << 17)   (needs N < 131072), .y = w bits

__global__ void k_bscatter(const int* __restrict__ row, const int* __restrict__ col,
                           const float* __restrict__ w, int E, int BN,
                           const int* __restrict__ bbase, int* __restrict__ bfill,
                           int2* __restrict__ bucket) {
  int e = blockIdx.x * blockDim.x + threadIdx.x;
  if (e >= E) return;
  int c = col[e];
  int b = c / BN;
  int lcol = c - b * BN;
  int p = atomicAdd(&bfill[b << 4], 1);
  bucket[bbase[b] + p] = make_int2(row[e] | (lcol << 17), __float_as_int(w[e]));
}

// ---- pass B: workgroup per bucket -> node-ordered CSR + cnt/start/dis/x8p --

__global__ void k_build(const int2* __restrict__ bucket, const int* __restrict__ bbase,
                        const float* __restrict__ x,
                        int2* __restrict__ csr, int* __restrict__ cnt,
                        int* __restrict__ start, float* __restrict__ dis,
                        float* __restrict__ x8p, int BN, int N) {
  __shared__ int   hist[BNMAX];
  __shared__ float wsum[BNMAX];
  __shared__ int   lstart[BNMAX + 1];
  __shared__ int   lfill[BNMAX];
  int b = blockIdx.x, t = threadIdx.x;
  int n0 = b * BN;
  int M = N - n0; if (M > BN) M = BN;
  if (M <= 0) return;
  if (t < BN) { hist[t] = 0; wsum[t] = 0.0f; lfill[t] = 0; }
  __syncthreads();
  int eb = bbase[b], ec = bbase[b + 1] - eb;
  // phase 1: per-node histogram + weight sum
  for (int i = t; i < ec; i += BLK) {
    int2 p = bucket[eb + i];
    int lc = ((unsigned)p.x) >> 17;
    atomicAdd(&hist[lc], 1);
    atomicAdd(&wsum[lc], __int_as_float(p.y));
  }
  __syncthreads();
  if (t == 0) {
    int run = 0;
    for (int i = 0; i < M; ++i) { lstart[i] = run; run += hist[i]; }
    lstart[M] = run;
  }
  __syncthreads();
  // per-node outputs
  if (t < M) {
    int n = n0 + t;
    cnt[n] = hist[t];
    start[n] = eb + lstart[t];
    float d = 1.0f / sqrtf(wsum[t] + 1.0f);
    dis[n] = d;
    const float* xr = x + (size_t)n * 6;
    float* xo = x8p + (size_t)n * 8;
#pragma unroll
    for (int k = 0; k < 6; ++k) xo[k] = d * xr[k];
    xo[6] = 0.0f; xo[7] = 0.0f;
  }
  // phase 3: scatter into node-ordered CSR (writes within a ~26 KB window)
  for (int i = t; i < ec; i += BLK) {
    int2 p = bucket[eb + i];
    int lc = ((unsigned)p.x) >> 17;
    int pos = lstart[lc] + atomicAdd(&lfill[lc], 1);
    csr[eb + pos] = make_int2(p.x & 0x1FFFF, p.y);
  }
}

// ---- layer 1: aggregate F=6 pre-scaled feats (thread/node) -----------------

__global__ void k_agg6(const float* __restrict__ x8p,
                       const int* __restrict__ start, const int* __restrict__ cnt,
                       const int2* __restrict__ csr, const float* __restrict__ dis,
                       float* __restrict__ agg6, int N) {
  int n = blockIdx.x * blockDim.x + threadIdx.x;
  if (n >= N) return;
  const float4* xr = (const float4*)(x8p + (size_t)n * 8);
  float4 lo = xr[0], hi = xr[1];             // self term = x'[n]
  int s = start[n], e = s + cnt[n];
  for (int i = s; i < e; ++i) {
    int2 p = csr[i];
    float v = __int_as_float(p.y);
    const float4* sr = (const float4*)(x8p + (size_t)p.x * 8);
    float4 a = sr[0], b = sr[1];
    lo.x += v * a.x; lo.y += v * a.y; lo.z += v * a.z; lo.w += v * a.w;
    hi.x += v * b.x; hi.y += v * b.y;
  }
  float d = dis[n];
  float* o = agg6 + (size_t)n * 8;
  o[0] = d * lo.x; o[1] = d * lo.y; o[2] = d * lo.z; o[3] = d * lo.w;
  o[4] = d * hi.x; o[5] = d * hi.y; o[6] = 0.0f; o[7] = 0.0f;
}

// dense 6->64 + bias + sigmoid, epilogue * dis  (produces h1' = dis*h1)
__global__ void k_dense6(const float* __restrict__ agg6, const float* __restrict__ W,
                         const float* __restrict__ b, const float* __restrict__ dis,
                         float* __restrict__ out, int N) {
  int idx = blockIdx.x * blockDim.x + threadIdx.x;
  if (idx >= N * 64) return;
  int n = idx >> 6, j = idx & 63;
  const float* ar = agg6 + (size_t)n * 8;
  float acc = b[j];
#pragma unroll
  for (int k = 0; k < 6; ++k) acc += ar[k] * W[k * 64 + j];
  out[idx] = dis[n] / (1.0f + expf(-acc));
}

// ---- layers 2/3 aggregation: 8 lanes/node, 2x float4 -> 8 streams/wave -----

__global__ void k_agg64(const float* __restrict__ hp,
                        const int* __restrict__ start, const int* __restrict__ cnt,
                        const int2* __restrict__ csr, const float* __restrict__ dis,
                        float* __restrict__ agg, int N) {
  int t = blockIdx.x * blockDim.x + threadIdx.x;
  int n = t >> 3, sub = t & 7;
  if (n >= N) return;
  const float* self = hp + (size_t)n * 64 + sub * 8;
  float4 a0 = *(const float4*)self;
  float4 a1 = *(const float4*)(self + 4);
  int s = start[n], e = s + cnt[n];
  for (int i = s; i < e; ++i) {
    int2 p = csr[i];                          // broadcast in 8-lane group
    float v = __int_as_float(p.y);
    const float* src = hp + (size_t)p.x * 64 + sub * 8;
    float4 h0 = *(const float4*)src;
    float4 h1 = *(const float4*)(src + 4);
    a0.x += v * h0.x; a0.y += v * h0.y; a0.z += v * h0.z; a0.w += v * h0.w;
    a1.x += v * h1.x; a1.y += v * h1.y; a1.z += v * h1.z; a1.w += v * h1.w;
  }
  float d = dis[n];
  a0.x *= d; a0.y *= d; a0.z *= d; a0.w *= d;
  a1.x *= d; a1.y *= d; a1.z *= d; a1.w *= d;
  float* o = agg + (size_t)n * 64 + sub * 8;
  *(float4*)o = a0;
  *(float4*)(o + 4) = a1;
}

// dense 64->64 + bias + sigmoid, epilogue * dis (produces h2')
__global__ void k_dense64(const float* __restrict__ aggIn, const float* __restrict__ W,
                          const float* __restrict__ b, const float* __restrict__ dis,
                          float* __restrict__ out, int N) {
  int idx = blockIdx.x * blockDim.x + threadIdx.x;
  if (idx >= N * 64) return;
  int n = idx >> 6, j = idx & 63;
  const float* ar = aggIn + (size_t)n * 64;   // wave-broadcast row
  float acc = b[j];
#pragma unroll 16
  for (int k = 0; k < 64; ++k) acc += ar[k] * W[k * 64 + j];
  out[idx] = dis[n] / (1.0f + expf(-acc));
}

// layer-3 dense + sigmoid + logits head fused: wave per node, j = lane.
__global__ void k_dense64_logits(const float* __restrict__ aggIn, const float* __restrict__ W,
                                 const float* __restrict__ b, const float* __restrict__ Wl,
                                 const float* __restrict__ bl, float* __restrict__ logits,
                                 int N) {
  int n = blockIdx.x * (blockDim.x >> 6) + (threadIdx.x >> 6);
  int j = threadIdx.x & 63;
  if (n >= N) return;
  const float* ar = aggIn + (size_t)n * 64;
  float acc = b[j];
#pragma unroll 16
  for (int k = 0; k < 64; ++k) acc += ar[k] * W[k * 64 + j];
  float h = 1.0f / (1.0f + expf(-acc));
  float p = h * Wl[j];
#pragma unroll
  for (int o = 32; o > 0; o >>= 1) p += __shfl_down(p, o, 64);
  if (j == 0) logits[n] = p + bl[0];
}

// ---- softmax over nodes ----------------------------------------------------

__device__ inline void atomicMaxF(float* addr, float val) {
  int old = __float_as_int(*addr);
  while (val > __int_as_float(old)) {
    int assumed = old;
    old = atomicCAS((int*)addr, assumed, __float_as_int(val));
    if (old == assumed) break;
  }
}

__global__ void k_max(const float* __restrict__ logits, int N, float* __restrict__ red) {
  int i = blockIdx.x * blockDim.x + threadIdx.x;
  float m = (i < N) ? logits[i] : -3.0e38f;
  int lane = threadIdx.x & 63, wid = threadIdx.x >> 6;
#pragma unroll
  for (int o = 32; o > 0; o >>= 1) m = fmaxf(m, __shfl_down(m, o, 64));
  __shared__ float sm[BLK / 64];
  if (lane == 0) sm[wid] = m;
  __syncthreads();
  if (threadIdx.x == 0) {
    float bm = sm[0];
    for (int k = 1; k < BLK / 64; ++k) bm = fmaxf(bm, sm[k]);
    atomicMaxF(&red[0], bm);
  }
}

__global__ void k_expsum(float* __restrict__ logits, int N, float* __restrict__ red) {
  float gm = red[0];
  int i = blockIdx.x * blockDim.x + threadIdx.x;
  float e = 0.0f;
  if (i < N) {
    e = expf(logits[i] - gm);
    logits[i] = e;
  }
  int lane = threadIdx.x & 63, wid = threadIdx.x >> 6;
#pragma unroll
  for (int o = 32; o > 0; o >>= 1) e += __shfl_down(e, o, 64);
  __shared__ float sm[BLK / 64];
  if (lane == 0) sm[wid] = e;
  __syncthreads();
  if (threadIdx.x == 0) {
    float bs = sm[0];
    for (int k = 1; k < BLK / 64; ++k) bs += sm[k];
    atomicAdd(&red[1], bs);
  }
}

__global__ void k_out(const float* __restrict__ e, int N, const float* __restrict__ red,
                      float* __restrict__ out) {
  int i = blockIdx.x * blockDim.x + threadIdx.x;
  if (i >= N) return;
  out[i] = e[i] * (1.0f / red[1]);
}

// ---------------------------------------------------------------------------

extern "C" void kernel_launch(void* const* d_in, const int* in_sizes, int n_in,
                              void* d_out, int out_size, void* d_ws, size_t ws_size,
                              hipStream_t stream) {
  const float* x   = (const float*)d_in[0];   // [N,6]
  const int*   edg = (const int*)d_in[1];     // [2,E] int32
  const float* w   = (const float*)d_in[2];   // [E]
  const float* W1  = (const float*)d_in[3];   // [6,64]
  const float* b1  = (const float*)d_in[4];
  const float* W2  = (const float*)d_in[5];   // [64,64]
  const float* b2  = (const float*)d_in[6];
  const float* W3  = (const float*)d_in[7];
  const float* b3  = (const float*)d_in[8];
  const float* Wl  = (const float*)d_in[9];   // [64,1]
  const float* bl  = (const float*)d_in[10];
  float* out = (float*)d_out;

  const int N = in_sizes[0] / 6;
  const int E = in_sizes[2];
  const int* row = edg;
  const int* col = edg + E;
  const int BN = (N + KB - 1) / KB;           // nodes per bucket (98), < BNMAX

  // ---- workspace layout ----
  size_t off = 0;
  char* base = (char*)d_ws;
  auto alloc = [&](size_t bytes) -> void* {
    void* p = base + off;
    off += (bytes + 255) & ~(size_t)255;
    return p;
  };
  int*   bcnt   = (int*)alloc((size_t)KB * 16 * 4);   // padded counters (zeroed)
  int*   bfill  = (int*)alloc((size_t)KB * 16 * 4);   // (zeroed)
  size_t zero_bytes = off;
  int*   bbase  = (int*)alloc((size_t)(KB + 1) * 4);
  int*   cnt    = (int*)alloc((size_t)N * 4);
  int*   start  = (int*)alloc((size_t)N * 4);
  float* dis    = (float*)alloc((size_t)N * 4);
  float* x8p    = (float*)alloc((size_t)N * 8 * 4);
  float* agg6   = (float*)alloc((size_t)N * 8 * 4);
  float* logits = (float*)alloc((size_t)N * 4);
  float* red    = (float*)alloc(2 * 4);
  int2*  csr    = (int2*)alloc((size_t)E * 8);
  float* bufA   = (float*)alloc((size_t)N * 64 * 4);
  // bufB aliases the bucket staging area: bucket dead after k_build,
  // bufB first written by the layer-2 k_agg64. Same size when E == 64*N/... -> take max.
  size_t bigsz = (size_t)N * 64 * 4;
  size_t bksz  = (size_t)E * 8;
  void*  shared_blk = alloc(bigsz > bksz ? bigsz : bksz);
  int2*  bucket = (int2*)shared_blk;
  float* bufB   = (float*)shared_blk;
  (void)ws_size;

  const int gE  = (E + BLK - 1) / BLK;
  const int gN  = (N + BLK - 1) / BLK;
  const int gNH = (N * 64 + BLK - 1) / BLK;     // thread per (n,j)
  const int gN8 = (N * 8 + BLK - 1) / BLK;      // 8 threads per node
  const int gNW = (N + 3) / 4;                  // wave per node

  hipMemsetAsync(d_ws, 0, zero_bytes, stream);

  // CSR build via two-level bucket sort (all writes line-sequential)
  k_bcount  <<<gE, BLK, 0, stream>>>(col, E, BN, bcnt);
  k_bscan   <<<1,  BLK, 0, stream>>>(bcnt, bbase, red, KB);
  k_bscatter<<<gE, BLK, 0, stream>>>(row, col, w, E, BN, bbase, bfill, bucket);
  k_build   <<<KB, BLK, 0, stream>>>(bucket, bbase, x, csr, cnt, start, dis, x8p, BN, N);

  // layer 1
  k_agg6  <<<gN,  BLK, 0, stream>>>(x8p, start, cnt, csr, dis, agg6, N);
  k_dense6<<<gNH, BLK, 0, stream>>>(agg6, W1, b1, dis, bufA, N);

  // layer 2
  k_agg64  <<<gN8, BLK, 0, stream>>>(bufA, start, cnt, csr, dis, bufB, N);
  k_dense64<<<gNH, BLK, 0, stream>>>(bufB, W2, b2, dis, bufA, N);

  // layer 3 (dense fused with logits head)
  k_agg64         <<<gN8, BLK, 0, stream>>>(bufA, start, cnt, csr, dis, bufB, N);
  k_dense64_logits<<<gNW, BLK, 0, stream>>>(bufB, W3, b3, Wl, bl, logits, N);

  // softmax over nodes
  k_max   <<<gN, BLK, 0, stream>>>(logits, N, red);
  k_expsum<<<gN, BLK, 0, stream>>>(logits, N, red);
  k_out   <<<gN, BLK, 0, stream>>>(logits, N, red, out);
}

// Round 5
// 384.717 us; speedup vs baseline: 1.2948x; 1.2948x over previous
//
#include <hip/hip_runtime.h>
#include <math.h>

// ---------------------------------------------------------------------------
// 3-layer GCN + softmax on MI355X, fp32 end-to-end.
// A(XW) = (AX)W -> aggregate first (F=6 for layer 1).
// R4: LDS-binned single-pass bucket scatter (block stages 4096 edges, sorts
//     by 256-node bucket in LDS, writes contiguous runs -> full HBM lines;
//     one global atomic per bucket per block). Fixed-capacity bucket regions
//     kill bcount/bscan; CSR keeps per-bucket layout (no global scan).
//     Softmax max-pass dropped (shift-invariant, logits bounded); exp+sum
//     fused into layer-3 dense. 9 launches total.
// ---------------------------------------------------------------------------

#define BLK 256
#define SKB 256            // scatter buckets: b = col >> 8 (196 active)
#define CHUNK 4096         // edges staged per block in k_binscatter

// ---- pass A: LDS-binned scatter into fixed-capacity bucket regions ---------
// Entry: .x = row | (col << 16)  (N < 65536), .y = float bits of w.

__global__ __launch_bounds__(256) void k_binscatter(
    const int* __restrict__ row, const int* __restrict__ col,
    const float* __restrict__ w, int E,
    int* __restrict__ bfill, int2* __restrict__ bucket, int CAP) {
  __shared__ int2 stage[CHUNK];
  __shared__ int lhist[SKB], lbase[SKB], gbase[SKB], lfill[SKB];
  int t = threadIdx.x;
  int e0 = blockIdx.x * CHUNK;
  int n = E - e0; if (n > CHUNK) n = CHUNK;
  lhist[t] = 0; lfill[t] = 0;
  __syncthreads();
  for (int i = t; i < n; i += BLK) atomicAdd(&lhist[((unsigned)col[e0 + i]) >> 8], 1);
  __syncthreads();
  // exclusive scan of lhist (Hillis-Steele over 256 = blockDim)
  lbase[t] = lhist[t];
  __syncthreads();
  for (int off = 1; off < SKB; off <<= 1) {
    int v = (t >= off) ? lbase[t - off] : 0;
    __syncthreads();
    lbase[t] += v;
    __syncthreads();
  }
  int excl = lbase[t] - lhist[t];
  int cb = lhist[t];
  gbase[t] = cb ? atomicAdd(&bfill[t << 4], cb) : 0;   // reserve run space
  __syncthreads();
  lbase[t] = excl;
  __syncthreads();
  // sort chunk by bucket into LDS
  for (int i = t; i < n; i += BLK) {
    int c = col[e0 + i];
    int b = ((unsigned)c) >> 8;
    int r = atomicAdd(&lfill[b], 1);
    stage[lbase[b] + r] = make_int2(row[e0 + i] | (c << 16), __float_as_int(w[e0 + i]));
  }
  __syncthreads();
  // write runs out contiguously (consecutive i in a run -> consecutive addr)
  for (int i = t; i < n; i += BLK) {
    int2 p = stage[i];
    int b = ((unsigned)p.x) >> 24;
    bucket[(size_t)b * CAP + gbase[b] + (i - lbase[b])] = p;
  }
}

// ---- pass B: workgroup per bucket -> node-ordered CSR + cnt/start/dis/x8p --

__global__ __launch_bounds__(256) void k_build(
    const int2* __restrict__ bucket, const int* __restrict__ bfill,
    const float* __restrict__ x,
    int2* __restrict__ csr, int* __restrict__ cnt, int* __restrict__ start,
    float* __restrict__ dis, float* __restrict__ x8p, int CAP, int N) {
  __shared__ int   hist[SKB];
  __shared__ float wsum[SKB];
  __shared__ int   lstart[SKB + 1];
  __shared__ int   lfill[SKB];
  int b = blockIdx.x, t = threadIdx.x;
  int n0 = b << 8;
  int M = N - n0; if (M > 256) M = 256;
  if (M <= 0) return;
  hist[t] = 0; wsum[t] = 0.0f; lfill[t] = 0;
  __syncthreads();
  const int2* bb = bucket + (size_t)b * CAP;
  int ec = bfill[b << 4];
  for (int i = t; i < ec; i += BLK) {
    int2 p = bb[i];
    int lc = (((unsigned)p.x) >> 16) & 255;
    atomicAdd(&hist[lc], 1);
    atomicAdd(&wsum[lc], __int_as_float(p.y));
  }
  __syncthreads();
  if (t == 0) {
    int run = 0;
    for (int i = 0; i < M; ++i) { lstart[i] = run; run += hist[i]; }
    lstart[M] = run;
  }
  __syncthreads();
  if (t < M) {
    int n = n0 + t;
    cnt[n] = hist[t];
    start[n] = b * CAP + lstart[t];
    float d = 1.0f / sqrtf(wsum[t] + 1.0f);
    dis[n] = d;
    const float* xr = x + (size_t)n * 6;
    float* xo = x8p + (size_t)n * 8;
#pragma unroll
    for (int k = 0; k < 6; ++k) xo[k] = d * xr[k];
    xo[6] = 0.0f; xo[7] = 0.0f;
  }
  __syncthreads();
  for (int i = t; i < ec; i += BLK) {
    int2 p = bb[i];
    int lc = (((unsigned)p.x) >> 16) & 255;
    int pos = lstart[lc] + atomicAdd(&lfill[lc], 1);
    csr[(size_t)b * CAP + pos] = make_int2(p.x & 0xFFFF, p.y);
  }
}

// ---- layer 1 fused: aggregate F=6 pre-scaled feats + dense 6->64 + sigmoid -

__global__ void k_layer1(const float* __restrict__ x8p,
                         const int* __restrict__ start, const int* __restrict__ cnt,
                         const int2* __restrict__ csr, const float* __restrict__ dis,
                         const float* __restrict__ W1, const float* __restrict__ b1,
                         float* __restrict__ out, int N) {
  int n = blockIdx.x * blockDim.x + threadIdx.x;
  if (n >= N) return;
  const float4* xr = (const float4*)(x8p + (size_t)n * 8);
  float4 lo = xr[0], hi = xr[1];                 // self term = x'[n]
  int s = start[n], e = s + cnt[n];
  for (int i = s; i < e; ++i) {
    int2 p = csr[i];
    float v = __int_as_float(p.y);
    const float4* sr = (const float4*)(x8p + (size_t)p.x * 8);
    float4 a = sr[0], b = sr[1];
    lo.x += v * a.x; lo.y += v * a.y; lo.z += v * a.z; lo.w += v * a.w;
    hi.x += v * b.x; hi.y += v * b.y;
  }
  float d = dis[n];
  float a0 = d * lo.x, a1 = d * lo.y, a2 = d * lo.z, a3 = d * lo.w;
  float a4 = d * hi.x, a5 = d * hi.y;
  float* o = out + (size_t)n * 64;
#pragma unroll
  for (int j4 = 0; j4 < 16; ++j4) {
    float4 acc = *(const float4*)(b1 + j4 * 4);
    const float* Wc = W1 + j4 * 4;
    acc.x += a0*Wc[0]   + a1*Wc[64]   + a2*Wc[128]   + a3*Wc[192]   + a4*Wc[256]   + a5*Wc[320];
    acc.y += a0*Wc[1]   + a1*Wc[65]   + a2*Wc[129]   + a3*Wc[193]   + a4*Wc[257]   + a5*Wc[321];
    acc.z += a0*Wc[2]   + a1*Wc[66]   + a2*Wc[130]   + a3*Wc[194]   + a4*Wc[258]   + a5*Wc[322];
    acc.w += a0*Wc[3]   + a1*Wc[67]   + a2*Wc[131]   + a3*Wc[195]   + a4*Wc[259]   + a5*Wc[323];
    float4 r;
    r.x = d / (1.0f + expf(-acc.x));
    r.y = d / (1.0f + expf(-acc.y));
    r.z = d / (1.0f + expf(-acc.z));
    r.w = d / (1.0f + expf(-acc.w));
    *(float4*)(o + j4 * 4) = r;                   // h1' = dis * h1
  }
}

// ---- layers 2/3 aggregation: 8 lanes/node, 2x float4 -> 8 streams/wave -----

__global__ void k_agg64(const float* __restrict__ hp,
                        const int* __restrict__ start, const int* __restrict__ cnt,
                        const int2* __restrict__ csr, const float* __restrict__ dis,
                        float* __restrict__ agg, int N) {
  int t = blockIdx.x * blockDim.x + threadIdx.x;
  int n = t >> 3, sub = t & 7;
  if (n >= N) return;
  const float* self = hp + (size_t)n * 64 + sub * 8;
  float4 a0 = *(const float4*)self;
  float4 a1 = *(const float4*)(self + 4);
  int s = start[n], e = s + cnt[n];
  for (int i = s; i < e; ++i) {
    int2 p = csr[i];                          // broadcast within 8-lane group
    float v = __int_as_float(p.y);
    const float* src = hp + (size_t)p.x * 64 + sub * 8;
    float4 h0 = *(const float4*)src;
    float4 h1 = *(const float4*)(src + 4);
    a0.x += v * h0.x; a0.y += v * h0.y; a0.z += v * h0.z; a0.w += v * h0.w;
    a1.x += v * h1.x; a1.y += v * h1.y; a1.z += v * h1.z; a1.w += v * h1.w;
  }
  float d = dis[n];
  a0.x *= d; a0.y *= d; a0.z *= d; a0.w *= d;
  a1.x *= d; a1.y *= d; a1.z *= d; a1.w *= d;
  float* o = agg + (size_t)n * 64 + sub * 8;
  *(float4*)o = a0;
  *(float4*)(o + 4) = a1;
}

// dense 64->64 + bias + sigmoid, epilogue * dis (produces h2')
__global__ void k_dense64(const float* __restrict__ aggIn, const float* __restrict__ W,
                          const float* __restrict__ b, const float* __restrict__ dis,
                          float* __restrict__ out, int N) {
  int idx = blockIdx.x * blockDim.x + threadIdx.x;
  if (idx >= N * 64) return;
  int n = idx >> 6, j = idx & 63;
  const float* ar = aggIn + (size_t)n * 64;   // wave-broadcast row
  float acc = b[j];
#pragma unroll 16
  for (int k = 0; k < 64; ++k) acc += ar[k] * W[k * 64 + j];
  out[idx] = dis[n] / (1.0f + expf(-acc));
}

// layer-3 dense + sigmoid + logit + exp + partial sum (no max shift needed:
// |logit| <= sum|Wl| + |bl| ~ 6, exp safe in fp32; softmax shift-invariant)
__global__ void k_dense64_head(const float* __restrict__ aggIn, const float* __restrict__ W,
                               const float* __restrict__ b, const float* __restrict__ Wl,
                               const float* __restrict__ bl, float* __restrict__ expv,
                               float* __restrict__ red_part, int N) {
  int wid = threadIdx.x >> 6;
  int n = blockIdx.x * 4 + wid;
  int j = threadIdx.x & 63;
  __shared__ float sm[4];
  if (n < N) {
    const float* ar = aggIn + (size_t)n * 64;
    float acc = b[j];
#pragma unroll 16
    for (int k = 0; k < 64; ++k) acc += ar[k] * W[k * 64 + j];
    float h = 1.0f / (1.0f + expf(-acc));
    float p = h * Wl[j];
#pragma unroll
    for (int o = 32; o > 0; o >>= 1) p += __shfl_down(p, o, 64);
    if (j == 0) { float ev = expf(p + bl[0]); expv[n] = ev; sm[wid] = ev; }
  } else if (j == 0) sm[wid] = 0.0f;
  __syncthreads();
  if (threadIdx.x == 0)
    atomicAdd(&red_part[(blockIdx.x & 63) << 4], sm[0] + sm[1] + sm[2] + sm[3]);
}

// scale by 1/sum (each wave reduces the 64 padded partials; L2-hot)
__global__ void k_out(const float* __restrict__ expv, int N,
                      const float* __restrict__ red_part, float* __restrict__ out) {
  int i = blockIdx.x * blockDim.x + threadIdx.x;
  int lane = threadIdx.x & 63;
  float s = red_part[lane << 4];
#pragma unroll
  for (int o = 32; o > 0; o >>= 1) s += __shfl_down(s, o, 64);
  s = __shfl(s, 0, 64);
  if (i < N) out[i] = expv[i] / s;
}

// ---------------------------------------------------------------------------

extern "C" void kernel_launch(void* const* d_in, const int* in_sizes, int n_in,
                              void* d_out, int out_size, void* d_ws, size_t ws_size,
                              hipStream_t stream) {
  const float* x   = (const float*)d_in[0];   // [N,6]
  const int*   edg = (const int*)d_in[1];     // [2,E] int32
  const float* w   = (const float*)d_in[2];   // [E]
  const float* W1  = (const float*)d_in[3];   // [6,64]
  const float* b1  = (const float*)d_in[4];
  const float* W2  = (const float*)d_in[5];   // [64,64]
  const float* b2  = (const float*)d_in[6];
  const float* W3  = (const float*)d_in[7];
  const float* b3  = (const float*)d_in[8];
  const float* Wl  = (const float*)d_in[9];   // [64,1]
  const float* bl  = (const float*)d_in[10];
  float* out = (float*)d_out;

  const int N = in_sizes[0] / 6;
  const int E = in_sizes[2];
  const int* row = edg;
  const int* col = edg + E;
  const int NB = (N + 255) >> 8;              // active buckets (196)

  // ---- workspace layout ----
  size_t off = 0;
  char* base = (char*)d_ws;
  auto alloc = [&](size_t bytes) -> void* {
    void* p = base + off;
    off += (bytes + 255) & ~(size_t)255;
    return p;
  };
  int*   bfill    = (int*)alloc((size_t)SKB * 16 * 4);   // padded counters (zeroed)
  float* red_part = (float*)alloc((size_t)64 * 16 * 4);  // padded partials (zeroed)
  size_t zero_bytes = off;
  int*   cnt    = (int*)alloc((size_t)N * 4);
  int*   start  = (int*)alloc((size_t)N * 4);
  float* dis    = (float*)alloc((size_t)N * 4);
  float* x8p    = (float*)alloc((size_t)N * 8 * 4);
  float* expv   = (float*)alloc((size_t)N * 4);
  float* bufA   = (float*)alloc((size_t)N * 64 * 4);
  // bucket capacity from remaining ws: csr (NB*CAP*8) + shared blk
  // (max(bucket, bufB) = NB*CAP*8 for CAP >= 8192). Mean fill 8192, sigma 90.
  size_t remain = (ws_size > off) ? (ws_size - off) : 0;
  int CAP = (int)(remain / ((size_t)NB * 16));
  if (CAP > 9216) CAP = 9216;
  if (CAP < 8704) CAP = 8704;                 // mean + 5.7 sigma floor
  int2* csr = (int2*)alloc((size_t)NB * CAP * 8);
  size_t bigsz = (size_t)N * 64 * 4, bksz = (size_t)NB * CAP * 8;
  void* shared_blk = alloc(bigsz > bksz ? bigsz : bksz);
  int2*  bucket = (int2*)shared_blk;          // dead after k_build
  float* bufB   = (float*)shared_blk;

  const int gE  = (E + CHUNK - 1) / CHUNK;
  const int gN  = (N + BLK - 1) / BLK;
  const int gNH = (N * 64 + BLK - 1) / BLK;   // thread per (n,j)
  const int gN8 = (N * 8 + BLK - 1) / BLK;    // 8 threads per node
  const int gNW = (N + 3) / 4;                // wave per node

  hipMemsetAsync(d_ws, 0, zero_bytes, stream);

  // CSR build: LDS-binned scatter + per-bucket sort
  k_binscatter<<<gE, BLK, 0, stream>>>(row, col, w, E, bfill, bucket, CAP);
  k_build     <<<NB, BLK, 0, stream>>>(bucket, bfill, x, csr, cnt, start, dis, x8p, CAP, N);

  // layer 1 (fused agg + dense + sigmoid)
  k_layer1<<<gN, BLK, 0, stream>>>(x8p, start, cnt, csr, dis, W1, b1, bufA, N);

  // layer 2
  k_agg64  <<<gN8, BLK, 0, stream>>>(bufA, start, cnt, csr, dis, bufB, N);
  k_dense64<<<gNH, BLK, 0, stream>>>(bufB, W2, b2, dis, bufA, N);

  // layer 3 (dense fused with logits head + exp + partial sums)
  k_agg64       <<<gN8, BLK, 0, stream>>>(bufA, start, cnt, csr, dis, bufB, N);
  k_dense64_head<<<gNW, BLK, 0, stream>>>(bufB, W3, b3, Wl, bl, expv, red_part, N);

  // normalize
  k_out<<<gN, BLK, 0, stream>>>(expv, N, red_part, out);
}

// Round 6
// 340.365 us; speedup vs baseline: 1.4636x; 1.1303x over previous
//
#include <hip/hip_runtime.h>
#include <math.h>

// ---------------------------------------------------------------------------
// 3-layer GCN + softmax on MI355X.
// A(XW) = (AX)W -> aggregate first (F=6 for layer 1).
// R5: hidden activations h' = dis*h stored as bf16 (128 B rows -> half the
//     gather bytes, 6.4 MB L2 footprint); CSR entry packed to one uint32
//     (src | bf16(w) << 16). Accumulation and agg buffers stay fp32.
//     LDS-binned scatter (R4) unchanged. 9 launches.
// ---------------------------------------------------------------------------

#define BLK 256
#define SKB 256            // scatter buckets: b = col >> 8 (196 active)
#define CHUNK 4096         // edges staged per block in k_binscatter

__device__ inline unsigned short f2bf(float f) {      // fp32 -> bf16 (RNE)
  unsigned u = __float_as_uint(f);
  return (unsigned short)((u + 0x7FFF + ((u >> 16) & 1)) >> 16);
}
__device__ inline float bflo(unsigned u) { return __uint_as_float(u << 16); }
__device__ inline float bfhi(unsigned u) { return __uint_as_float(u & 0xFFFF0000u); }

// ---- pass A: LDS-binned scatter into fixed-capacity bucket regions ---------
// Entry: .x = row | (col << 16)  (N < 65536), .y = float bits of w.

__global__ __launch_bounds__(256) void k_binscatter(
    const int* __restrict__ row, const int* __restrict__ col,
    const float* __restrict__ w, int E,
    int* __restrict__ bfill, int2* __restrict__ bucket, int CAP) {
  __shared__ int2 stage[CHUNK];
  __shared__ int lhist[SKB], lbase[SKB], gbase[SKB], lfill[SKB];
  int t = threadIdx.x;
  int e0 = blockIdx.x * CHUNK;
  int n = E - e0; if (n > CHUNK) n = CHUNK;
  lhist[t] = 0; lfill[t] = 0;
  __syncthreads();
  for (int i = t; i < n; i += BLK) atomicAdd(&lhist[((unsigned)col[e0 + i]) >> 8], 1);
  __syncthreads();
  lbase[t] = lhist[t];
  __syncthreads();
  for (int off = 1; off < SKB; off <<= 1) {
    int v = (t >= off) ? lbase[t - off] : 0;
    __syncthreads();
    lbase[t] += v;
    __syncthreads();
  }
  int excl = lbase[t] - lhist[t];
  int cb = lhist[t];
  gbase[t] = cb ? atomicAdd(&bfill[t << 4], cb) : 0;   // reserve run space
  __syncthreads();
  lbase[t] = excl;
  __syncthreads();
  for (int i = t; i < n; i += BLK) {
    int c = col[e0 + i];
    int b = ((unsigned)c) >> 8;
    int r = atomicAdd(&lfill[b], 1);
    stage[lbase[b] + r] = make_int2(row[e0 + i] | (c << 16), __float_as_int(w[e0 + i]));
  }
  __syncthreads();
  for (int i = t; i < n; i += BLK) {
    int2 p = stage[i];
    int b = ((unsigned)p.x) >> 24;
    bucket[(size_t)b * CAP + gbase[b] + (i - lbase[b])] = p;
  }
}

// ---- pass B: workgroup per bucket -> node-ordered packed CSR + norms -------

__global__ __launch_bounds__(256) void k_build(
    const int2* __restrict__ bucket, const int* __restrict__ bfill,
    const float* __restrict__ x,
    unsigned* __restrict__ csr, int* __restrict__ cnt, int* __restrict__ start,
    float* __restrict__ dis, float* __restrict__ x8p, int CAP, int N) {
  __shared__ int   hist[SKB];
  __shared__ float wsum[SKB];
  __shared__ int   lstart[SKB + 1];
  __shared__ int   lfill[SKB];
  int b = blockIdx.x, t = threadIdx.x;
  int n0 = b << 8;
  int M = N - n0; if (M > 256) M = 256;
  if (M <= 0) return;
  hist[t] = 0; wsum[t] = 0.0f; lfill[t] = 0;
  __syncthreads();
  const int2* bb = bucket + (size_t)b * CAP;
  int ec = bfill[b << 4];
  for (int i = t; i < ec; i += BLK) {
    int2 p = bb[i];
    int lc = (((unsigned)p.x) >> 16) & 255;
    atomicAdd(&hist[lc], 1);
    atomicAdd(&wsum[lc], __int_as_float(p.y));          // exact fp32 degree
  }
  __syncthreads();
  if (t == 0) {
    int run = 0;
    for (int i = 0; i < M; ++i) { lstart[i] = run; run += hist[i]; }
    lstart[M] = run;
  }
  __syncthreads();
  if (t < M) {
    int n = n0 + t;
    cnt[n] = hist[t];
    start[n] = b * CAP + lstart[t];
    float d = 1.0f / sqrtf(wsum[t] + 1.0f);
    dis[n] = d;
    const float* xr = x + (size_t)n * 6;
    float* xo = x8p + (size_t)n * 8;
#pragma unroll
    for (int k = 0; k < 6; ++k) xo[k] = d * xr[k];
    xo[6] = 0.0f; xo[7] = 0.0f;
  }
  __syncthreads();
  for (int i = t; i < ec; i += BLK) {
    int2 p = bb[i];
    int lc = (((unsigned)p.x) >> 16) & 255;
    int pos = lstart[lc] + atomicAdd(&lfill[lc], 1);
    // packed: src (low 16) | bf16 weight (high 16)
    csr[(size_t)b * CAP + pos] =
        ((unsigned)p.x & 0xFFFFu) | ((unsigned)f2bf(__int_as_float(p.y)) << 16);
  }
}

// ---- layer 1 fused: aggregate F=6 pre-scaled feats + dense 6->64 + sigmoid -
// Output h1' = dis*h1 as bf16 rows.

__global__ void k_layer1(const float* __restrict__ x8p,
                         const int* __restrict__ start, const int* __restrict__ cnt,
                         const unsigned* __restrict__ csr, const float* __restrict__ dis,
                         const float* __restrict__ W1, const float* __restrict__ b1,
                         unsigned short* __restrict__ hb, int N) {
  int n = blockIdx.x * blockDim.x + threadIdx.x;
  if (n >= N) return;
  const float4* xr = (const float4*)(x8p + (size_t)n * 8);
  float4 lo = xr[0], hi = xr[1];                 // self term = x'[n]
  int s = start[n], e = s + cnt[n];
  for (int i = s; i < e; ++i) {
    unsigned pe = csr[i];
    float v = bfhi(pe);
    const float4* sr = (const float4*)(x8p + (size_t)(pe & 0xFFFFu) * 8);
    float4 a = sr[0], b = sr[1];
    lo.x += v * a.x; lo.y += v * a.y; lo.z += v * a.z; lo.w += v * a.w;
    hi.x += v * b.x; hi.y += v * b.y;
  }
  float d = dis[n];
  float a0 = d * lo.x, a1 = d * lo.y, a2 = d * lo.z, a3 = d * lo.w;
  float a4 = d * hi.x, a5 = d * hi.y;
  unsigned short* o = hb + (size_t)n * 64;
#pragma unroll
  for (int j4 = 0; j4 < 16; ++j4) {
    float4 acc = *(const float4*)(b1 + j4 * 4);
    const float* Wc = W1 + j4 * 4;
    acc.x += a0*Wc[0] + a1*Wc[64] + a2*Wc[128] + a3*Wc[192] + a4*Wc[256] + a5*Wc[320];
    acc.y += a0*Wc[1] + a1*Wc[65] + a2*Wc[129] + a3*Wc[193] + a4*Wc[257] + a5*Wc[321];
    acc.z += a0*Wc[2] + a1*Wc[66] + a2*Wc[130] + a3*Wc[194] + a4*Wc[258] + a5*Wc[322];
    acc.w += a0*Wc[3] + a1*Wc[67] + a2*Wc[131] + a3*Wc[195] + a4*Wc[259] + a5*Wc[323];
    uint2 pk;
    pk.x = (unsigned)f2bf(d / (1.0f + expf(-acc.x))) |
           ((unsigned)f2bf(d / (1.0f + expf(-acc.y))) << 16);
    pk.y = (unsigned)f2bf(d / (1.0f + expf(-acc.z))) |
           ((unsigned)f2bf(d / (1.0f + expf(-acc.w))) << 16);
    *(uint2*)(o + j4 * 4) = pk;
  }
}

// ---- layers 2/3 aggregation: 8 lanes/node, 16B bf16 loads (8 streams/wave) -

__global__ void k_agg64(const unsigned short* __restrict__ hb,
                        const int* __restrict__ start, const int* __restrict__ cnt,
                        const unsigned* __restrict__ csr, const float* __restrict__ dis,
                        float* __restrict__ agg, int N) {
  int t = blockIdx.x * blockDim.x + threadIdx.x;
  int n = t >> 3, sub = t & 7;
  if (n >= N) return;
  uint4 sv = *(const uint4*)(hb + (size_t)n * 64 + sub * 8);   // self = h'[n]
  float a0 = bflo(sv.x), a1 = bfhi(sv.x), a2 = bflo(sv.y), a3 = bfhi(sv.y);
  float a4 = bflo(sv.z), a5 = bfhi(sv.z), a6 = bflo(sv.w), a7 = bfhi(sv.w);
  int s = start[n], e = s + cnt[n];
  for (int i = s; i < e; ++i) {
    unsigned pe = csr[i];                    // broadcast within 8-lane group
    float v = bfhi(pe);
    uint4 hv = *(const uint4*)(hb + (size_t)(pe & 0xFFFFu) * 64 + sub * 8); // 128B/row
    a0 += v * bflo(hv.x); a1 += v * bfhi(hv.x);
    a2 += v * bflo(hv.y); a3 += v * bfhi(hv.y);
    a4 += v * bflo(hv.z); a5 += v * bfhi(hv.z);
    a6 += v * bflo(hv.w); a7 += v * bfhi(hv.w);
  }
  float d = dis[n];
  float* o = agg + (size_t)n * 64 + sub * 8;
  *(float4*)o       = make_float4(d * a0, d * a1, d * a2, d * a3);
  *(float4*)(o + 4) = make_float4(d * a4, d * a5, d * a6, d * a7);
}

// dense 64->64 + bias + sigmoid, epilogue * dis, bf16 out (produces h2')
__global__ void k_dense64(const float* __restrict__ aggIn, const float* __restrict__ W,
                          const float* __restrict__ b, const float* __restrict__ dis,
                          unsigned short* __restrict__ hb, int N) {
  int idx = blockIdx.x * blockDim.x + threadIdx.x;
  if (idx >= N * 64) return;
  int n = idx >> 6, j = idx & 63;
  const float* ar = aggIn + (size_t)n * 64;   // wave-broadcast row
  float acc = b[j];
#pragma unroll 16
  for (int k = 0; k < 64; ++k) acc += ar[k] * W[k * 64 + j];
  hb[idx] = f2bf(dis[n] / (1.0f + expf(-acc)));
}

// layer-3 dense + sigmoid + logit + exp + partial sum (no max shift needed:
// |logit| <= sum|Wl| + |bl| ~ 6, exp safe in fp32; softmax shift-invariant)
__global__ void k_dense64_head(const float* __restrict__ aggIn, const float* __restrict__ W,
                               const float* __restrict__ b, const float* __restrict__ Wl,
                               const float* __restrict__ bl, float* __restrict__ expv,
                               float* __restrict__ red_part, int N) {
  int wid = threadIdx.x >> 6;
  int n = blockIdx.x * 4 + wid;
  int j = threadIdx.x & 63;
  __shared__ float sm[4];
  if (n < N) {
    const float* ar = aggIn + (size_t)n * 64;
    float acc = b[j];
#pragma unroll 16
    for (int k = 0; k < 64; ++k) acc += ar[k] * W[k * 64 + j];
    float h = 1.0f / (1.0f + expf(-acc));
    float p = h * Wl[j];
#pragma unroll
    for (int o = 32; o > 0; o >>= 1) p += __shfl_down(p, o, 64);
    if (j == 0) { float ev = expf(p + bl[0]); expv[n] = ev; sm[wid] = ev; }
  } else if (j == 0) sm[wid] = 0.0f;
  __syncthreads();
  if (threadIdx.x == 0)
    atomicAdd(&red_part[(blockIdx.x & 63) << 4], sm[0] + sm[1] + sm[2] + sm[3]);
}

// scale by 1/sum (each wave reduces the 64 padded partials; L2-hot)
__global__ void k_out(const float* __restrict__ expv, int N,
                      const float* __restrict__ red_part, float* __restrict__ out) {
  int i = blockIdx.x * blockDim.x + threadIdx.x;
  int lane = threadIdx.x & 63;
  float s = red_part[lane << 4];
#pragma unroll
  for (int o = 32; o > 0; o >>= 1) s += __shfl_down(s, o, 64);
  s = __shfl(s, 0, 64);
  if (i < N) out[i] = expv[i] / s;
}

// ---------------------------------------------------------------------------

extern "C" void kernel_launch(void* const* d_in, const int* in_sizes, int n_in,
                              void* d_out, int out_size, void* d_ws, size_t ws_size,
                              hipStream_t stream) {
  const float* x   = (const float*)d_in[0];   // [N,6]
  const int*   edg = (const int*)d_in[1];     // [2,E] int32
  const float* w   = (const float*)d_in[2];   // [E]
  const float* W1  = (const float*)d_in[3];   // [6,64]
  const float* b1  = (const float*)d_in[4];
  const float* W2  = (const float*)d_in[5];   // [64,64]
  const float* b2  = (const float*)d_in[6];
  const float* W3  = (const float*)d_in[7];
  const float* b3  = (const float*)d_in[8];
  const float* Wl  = (const float*)d_in[9];   // [64,1]
  const float* bl  = (const float*)d_in[10];
  float* out = (float*)d_out;

  const int N = in_sizes[0] / 6;
  const int E = in_sizes[2];
  const int* row = edg;
  const int* col = edg + E;
  const int NB = (N + 255) >> 8;              // active buckets (196)

  // ---- workspace layout ----
  size_t off = 0;
  char* base = (char*)d_ws;
  auto alloc = [&](size_t bytes) -> void* {
    void* p = base + off;
    off += (bytes + 255) & ~(size_t)255;
    return p;
  };
  int*   bfill    = (int*)alloc((size_t)SKB * 16 * 4);   // padded counters (zeroed)
  float* red_part = (float*)alloc((size_t)64 * 16 * 4);  // padded partials (zeroed)
  size_t zero_bytes = off;
  int*   cnt    = (int*)alloc((size_t)N * 4);
  int*   start  = (int*)alloc((size_t)N * 4);
  float* dis    = (float*)alloc((size_t)N * 4);
  float* x8p    = (float*)alloc((size_t)N * 8 * 4);
  float* expv   = (float*)alloc((size_t)N * 4);
  unsigned short* hb = (unsigned short*)alloc((size_t)N * 64 * 2);  // bf16 h'
  // packed CSR (uint32/edge) + shared block (bucket staging, then fp32 agg)
  size_t remain = (ws_size > off) ? (ws_size - off) : 0;
  size_t aggsz = (size_t)N * 64 * 4;
  long long capn = ((long long)remain - (long long)aggsz) / ((long long)NB * 12);
  int CAP = (int)capn;
  if (CAP > 9216) CAP = 9216;
  if (CAP < 8704) CAP = 8704;                 // mean 8163 + ~6 sigma floor
  unsigned* csr = (unsigned*)alloc((size_t)NB * CAP * 4);
  size_t bksz = (size_t)NB * CAP * 8;
  void* shared_blk = alloc(aggsz > bksz ? aggsz : bksz);
  int2*  bucket = (int2*)shared_blk;          // dead after k_build
  float* agg    = (float*)shared_blk;         // fp32 aggregation buffer

  const int gE  = (E + CHUNK - 1) / CHUNK;
  const int gN  = (N + BLK - 1) / BLK;
  const int gNH = (N * 64 + BLK - 1) / BLK;   // thread per (n,j)
  const int gN8 = (N * 8 + BLK - 1) / BLK;    // 8 threads per node
  const int gNW = (N + 3) / 4;                // wave per node

  hipMemsetAsync(d_ws, 0, zero_bytes, stream);

  // CSR build: LDS-binned scatter + per-bucket sort
  k_binscatter<<<gE, BLK, 0, stream>>>(row, col, w, E, bfill, bucket, CAP);
  k_build     <<<NB, BLK, 0, stream>>>(bucket, bfill, x, csr, cnt, start, dis, x8p, CAP, N);

  // layer 1 (fused agg + dense + sigmoid) -> hb (bf16)
  k_layer1<<<gN, BLK, 0, stream>>>(x8p, start, cnt, csr, dis, W1, b1, hb, N);

  // layer 2: agg (bf16 gather -> fp32) ; dense -> hb (bf16)
  k_agg64  <<<gN8, BLK, 0, stream>>>(hb, start, cnt, csr, dis, agg, N);
  k_dense64<<<gNH, BLK, 0, stream>>>(agg, W2, b2, dis, hb, N);

  // layer 3: agg ; dense fused with logits head + exp + partial sums
  k_agg64       <<<gN8, BLK, 0, stream>>>(hb, start, cnt, csr, dis, agg, N);
  k_dense64_head<<<gNW, BLK, 0, stream>>>(agg, W3, b3, Wl, bl, expv, red_part, N);

  // normalize
  k_out<<<gN, BLK, 0, stream>>>(expv, N, red_part, out);
}

// Round 7
// 263.572 us; speedup vs baseline: 1.8900x; 1.2914x over previous
//
#include <hip/hip_runtime.h>
#include <math.h>

// ---------------------------------------------------------------------------
// 3-layer GCN + softmax on MI355X.
// A(XW) = (AX)W -> aggregate first (F=6 for layer 1).
// R6: dense 64x64 layers moved to MFMA (bf16 in, fp32 acc). agg rows stored
//     bf16 -> MFMA A-frags are one 16B load. W in registers as B-frags,
//     loaded once per wave, amortized over ~4 strips (grid-stride).
//     Head logit reduced with quad butterfly; one atomic per wave.
// ---------------------------------------------------------------------------

#define BLK 256
#define SKB 256            // scatter buckets: b = col >> 8 (196 active)
#define CHUNK 4096         // edges staged per block in k_binscatter

typedef __attribute__((ext_vector_type(8))) short bf16x8;
typedef __attribute__((ext_vector_type(4))) float f32x4;

__device__ inline unsigned short f2bf(float f) {      // fp32 -> bf16 (RNE)
  unsigned u = __float_as_uint(f);
  return (unsigned short)((u + 0x7FFF + ((u >> 16) & 1)) >> 16);
}
__device__ inline float bflo(unsigned u) { return __uint_as_float(u << 16); }
__device__ inline float bfhi(unsigned u) { return __uint_as_float(u & 0xFFFF0000u); }

// ---- pass A: LDS-binned scatter into fixed-capacity bucket regions ---------
// Entry: .x = row | (col << 16)  (N < 65536), .y = float bits of w.

__global__ __launch_bounds__(256) void k_binscatter(
    const int* __restrict__ row, const int* __restrict__ col,
    const float* __restrict__ w, int E,
    int* __restrict__ bfill, int2* __restrict__ bucket, int CAP) {
  __shared__ int2 stage[CHUNK];
  __shared__ int lhist[SKB], lbase[SKB], gbase[SKB], lfill[SKB];
  int t = threadIdx.x;
  int e0 = blockIdx.x * CHUNK;
  int n = E - e0; if (n > CHUNK) n = CHUNK;
  lhist[t] = 0; lfill[t] = 0;
  __syncthreads();
  for (int i = t; i < n; i += BLK) atomicAdd(&lhist[((unsigned)col[e0 + i]) >> 8], 1);
  __syncthreads();
  lbase[t] = lhist[t];
  __syncthreads();
  for (int off = 1; off < SKB; off <<= 1) {
    int v = (t >= off) ? lbase[t - off] : 0;
    __syncthreads();
    lbase[t] += v;
    __syncthreads();
  }
  int excl = lbase[t] - lhist[t];
  int cb = lhist[t];
  gbase[t] = cb ? atomicAdd(&bfill[t << 4], cb) : 0;   // reserve run space
  __syncthreads();
  lbase[t] = excl;
  __syncthreads();
  for (int i = t; i < n; i += BLK) {
    int c = col[e0 + i];
    int b = ((unsigned)c) >> 8;
    int r = atomicAdd(&lfill[b], 1);
    stage[lbase[b] + r] = make_int2(row[e0 + i] | (c << 16), __float_as_int(w[e0 + i]));
  }
  __syncthreads();
  for (int i = t; i < n; i += BLK) {
    int2 p = stage[i];
    int b = ((unsigned)p.x) >> 24;
    bucket[(size_t)b * CAP + gbase[b] + (i - lbase[b])] = p;
  }
}

// ---- pass B: workgroup per bucket -> node-ordered packed CSR + norms -------

__global__ __launch_bounds__(256) void k_build(
    const int2* __restrict__ bucket, const int* __restrict__ bfill,
    const float* __restrict__ x,
    unsigned* __restrict__ csr, int* __restrict__ cnt, int* __restrict__ start,
    float* __restrict__ dis, float* __restrict__ x8p, int CAP, int N) {
  __shared__ int   hist[SKB];
  __shared__ float wsum[SKB];
  __shared__ int   lstart[SKB + 1];
  __shared__ int   lfill[SKB];
  int b = blockIdx.x, t = threadIdx.x;
  int n0 = b << 8;
  int M = N - n0; if (M > 256) M = 256;
  if (M <= 0) return;
  hist[t] = 0; wsum[t] = 0.0f; lfill[t] = 0;
  __syncthreads();
  const int2* bb = bucket + (size_t)b * CAP;
  int ec = bfill[b << 4];
  for (int i = t; i < ec; i += BLK) {
    int2 p = bb[i];
    int lc = (((unsigned)p.x) >> 16) & 255;
    atomicAdd(&hist[lc], 1);
    atomicAdd(&wsum[lc], __int_as_float(p.y));          // exact fp32 degree
  }
  __syncthreads();
  if (t == 0) {
    int run = 0;
    for (int i = 0; i < M; ++i) { lstart[i] = run; run += hist[i]; }
    lstart[M] = run;
  }
  __syncthreads();
  if (t < M) {
    int n = n0 + t;
    cnt[n] = hist[t];
    start[n] = b * CAP + lstart[t];
    float d = 1.0f / sqrtf(wsum[t] + 1.0f);
    dis[n] = d;
    const float* xr = x + (size_t)n * 6;
    float* xo = x8p + (size_t)n * 8;
#pragma unroll
    for (int k = 0; k < 6; ++k) xo[k] = d * xr[k];
    xo[6] = 0.0f; xo[7] = 0.0f;
  }
  __syncthreads();
  for (int i = t; i < ec; i += BLK) {
    int2 p = bb[i];
    int lc = (((unsigned)p.x) >> 16) & 255;
    int pos = lstart[lc] + atomicAdd(&lfill[lc], 1);
    csr[(size_t)b * CAP + pos] =
        ((unsigned)p.x & 0xFFFFu) | ((unsigned)f2bf(__int_as_float(p.y)) << 16);
  }
}

// ---- W fp32 -> bf16 prep ---------------------------------------------------

__global__ void k_wprep(const float* __restrict__ W2, const float* __restrict__ W3,
                        unsigned short* __restrict__ W2b, unsigned short* __restrict__ W3b) {
  int i = blockIdx.x * blockDim.x + threadIdx.x;
  if (i < 4096) { W2b[i] = f2bf(W2[i]); W3b[i] = f2bf(W3[i]); }
}

// ---- layer 1 fused: aggregate F=6 pre-scaled feats + dense 6->64 + sigmoid -

__global__ void k_layer1(const float* __restrict__ x8p,
                         const int* __restrict__ start, const int* __restrict__ cnt,
                         const unsigned* __restrict__ csr, const float* __restrict__ dis,
                         const float* __restrict__ W1, const float* __restrict__ b1,
                         unsigned short* __restrict__ hb, int N) {
  int n = blockIdx.x * blockDim.x + threadIdx.x;
  if (n >= N) return;
  const float4* xr = (const float4*)(x8p + (size_t)n * 8);
  float4 lo = xr[0], hi = xr[1];                 // self term = x'[n]
  int s = start[n], e = s + cnt[n];
  for (int i = s; i < e; ++i) {
    unsigned pe = csr[i];
    float v = bfhi(pe);
    const float4* sr = (const float4*)(x8p + (size_t)(pe & 0xFFFFu) * 8);
    float4 a = sr[0], b = sr[1];
    lo.x += v * a.x; lo.y += v * a.y; lo.z += v * a.z; lo.w += v * a.w;
    hi.x += v * b.x; hi.y += v * b.y;
  }
  float d = dis[n];
  float a0 = d * lo.x, a1 = d * lo.y, a2 = d * lo.z, a3 = d * lo.w;
  float a4 = d * hi.x, a5 = d * hi.y;
  unsigned short* o = hb + (size_t)n * 64;
#pragma unroll
  for (int j4 = 0; j4 < 16; ++j4) {
    float4 acc = *(const float4*)(b1 + j4 * 4);
    const float* Wc = W1 + j4 * 4;
    acc.x += a0*Wc[0] + a1*Wc[64] + a2*Wc[128] + a3*Wc[192] + a4*Wc[256] + a5*Wc[320];
    acc.y += a0*Wc[1] + a1*Wc[65] + a2*Wc[129] + a3*Wc[193] + a4*Wc[257] + a5*Wc[321];
    acc.z += a0*Wc[2] + a1*Wc[66] + a2*Wc[130] + a3*Wc[194] + a4*Wc[258] + a5*Wc[322];
    acc.w += a0*Wc[3] + a1*Wc[67] + a2*Wc[131] + a3*Wc[195] + a4*Wc[259] + a5*Wc[323];
    uint2 pk;
    pk.x = (unsigned)f2bf(d / (1.0f + expf(-acc.x))) |
           ((unsigned)f2bf(d / (1.0f + expf(-acc.y))) << 16);
    pk.y = (unsigned)f2bf(d / (1.0f + expf(-acc.z))) |
           ((unsigned)f2bf(d / (1.0f + expf(-acc.w))) << 16);
    *(uint2*)(o + j4 * 4) = pk;
  }
}

// ---- layers 2/3 aggregation: 8 lanes/node, 16B bf16 loads, bf16 out --------

__global__ void k_agg64(const unsigned short* __restrict__ hb,
                        const int* __restrict__ start, const int* __restrict__ cnt,
                        const unsigned* __restrict__ csr, const float* __restrict__ dis,
                        unsigned short* __restrict__ aggb, int N) {
  int t = blockIdx.x * blockDim.x + threadIdx.x;
  int n = t >> 3, sub = t & 7;
  if (n >= N) return;
  uint4 sv = *(const uint4*)(hb + (size_t)n * 64 + sub * 8);   // self = h'[n]
  float a0 = bflo(sv.x), a1 = bfhi(sv.x), a2 = bflo(sv.y), a3 = bfhi(sv.y);
  float a4 = bflo(sv.z), a5 = bfhi(sv.z), a6 = bflo(sv.w), a7 = bfhi(sv.w);
  int s = start[n], e = s + cnt[n];
  for (int i = s; i < e; ++i) {
    unsigned pe = csr[i];                    // broadcast within 8-lane group
    float v = bfhi(pe);
    uint4 hv = *(const uint4*)(hb + (size_t)(pe & 0xFFFFu) * 64 + sub * 8); // 128B/row
    a0 += v * bflo(hv.x); a1 += v * bfhi(hv.x);
    a2 += v * bflo(hv.y); a3 += v * bfhi(hv.y);
    a4 += v * bflo(hv.z); a5 += v * bfhi(hv.z);
    a6 += v * bflo(hv.w); a7 += v * bfhi(hv.w);
  }
  float d = dis[n];
  uint4 pk;
  pk.x = (unsigned)f2bf(d * a0) | ((unsigned)f2bf(d * a1) << 16);
  pk.y = (unsigned)f2bf(d * a2) | ((unsigned)f2bf(d * a3) << 16);
  pk.z = (unsigned)f2bf(d * a4) | ((unsigned)f2bf(d * a5) << 16);
  pk.w = (unsigned)f2bf(d * a6) | ((unsigned)f2bf(d * a7) << 16);
  *(uint4*)(aggb + (size_t)n * 64 + sub * 8) = pk;
}

// ---- MFMA dense 64->64 + bias + sigmoid + *dis -> bf16 h' ------------------
// Wave per 16-node strip (grid-stride). A[m=lane&15][k=quad*8+j] frags,
// B = W[k][col= jt*16 + (lane&15)], C/D: col=lane&15, row=quad*4+reg.

__global__ __launch_bounds__(256) void k_dense64_mfma(
    const unsigned short* __restrict__ aggb, const unsigned short* __restrict__ Wb,
    const float* __restrict__ b, const float* __restrict__ dis,
    unsigned short* __restrict__ hb, int NS) {
  int wid = threadIdx.x >> 6, lane = threadIdx.x & 63;
  int quad = lane >> 4, r16 = lane & 15;
  bf16x8 Bf[2][4];
#pragma unroll
  for (int kt = 0; kt < 2; ++kt)
#pragma unroll
    for (int jt = 0; jt < 4; ++jt)
#pragma unroll
      for (int j = 0; j < 8; ++j)
        Bf[kt][jt][j] = (short)Wb[(kt * 32 + quad * 8 + j) * 64 + jt * 16 + r16];
  float bias[4];
#pragma unroll
  for (int jt = 0; jt < 4; ++jt) bias[jt] = b[jt * 16 + r16];
  int stride = gridDim.x * 4;
  for (int s = blockIdx.x * 4 + wid; s < NS; s += stride) {
    int n0 = s * 16;
    bf16x8 Af0 = *(const bf16x8*)(aggb + (size_t)(n0 + r16) * 64 + quad * 8);
    bf16x8 Af1 = *(const bf16x8*)(aggb + (size_t)(n0 + r16) * 64 + 32 + quad * 8);
    f32x4 C[4];
#pragma unroll
    for (int jt = 0; jt < 4; ++jt) {
      f32x4 z = {0.f, 0.f, 0.f, 0.f};
      z = __builtin_amdgcn_mfma_f32_16x16x32_bf16(Af0, Bf[0][jt], z, 0, 0, 0);
      z = __builtin_amdgcn_mfma_f32_16x16x32_bf16(Af1, Bf[1][jt], z, 0, 0, 0);
      C[jt] = z;
    }
    float dv[4];
#pragma unroll
    for (int reg = 0; reg < 4; ++reg) dv[reg] = dis[n0 + quad * 4 + reg];
#pragma unroll
    for (int jt = 0; jt < 4; ++jt)
#pragma unroll
      for (int reg = 0; reg < 4; ++reg) {
        float h = dv[reg] / (1.0f + expf(-(C[jt][reg] + bias[jt])));
        hb[(size_t)(n0 + quad * 4 + reg) * 64 + jt * 16 + r16] = f2bf(h);
      }
  }
}

// ---- MFMA layer-3 dense + sigmoid + logit + exp + partial sum --------------

__global__ __launch_bounds__(256) void k_head_mfma(
    const unsigned short* __restrict__ aggb, const unsigned short* __restrict__ Wb,
    const float* __restrict__ b, const float* __restrict__ Wl,
    const float* __restrict__ bl, float* __restrict__ expv,
    float* __restrict__ red_part, int NS) {
  int wid = threadIdx.x >> 6, lane = threadIdx.x & 63;
  int quad = lane >> 4, r16 = lane & 15;
  bf16x8 Bf[2][4];
#pragma unroll
  for (int kt = 0; kt < 2; ++kt)
#pragma unroll
    for (int jt = 0; jt < 4; ++jt)
#pragma unroll
      for (int j = 0; j < 8; ++j)
        Bf[kt][jt][j] = (short)Wb[(kt * 32 + quad * 8 + j) * 64 + jt * 16 + r16];
  float bias[4], wlv[4];
#pragma unroll
  for (int jt = 0; jt < 4; ++jt) {
    bias[jt] = b[jt * 16 + r16];
    wlv[jt]  = Wl[jt * 16 + r16];
  }
  float bl0 = bl[0];
  float lsum = 0.0f;
  int stride = gridDim.x * 4;
  for (int s = blockIdx.x * 4 + wid; s < NS; s += stride) {
    int n0 = s * 16;
    bf16x8 Af0 = *(const bf16x8*)(aggb + (size_t)(n0 + r16) * 64 + quad * 8);
    bf16x8 Af1 = *(const bf16x8*)(aggb + (size_t)(n0 + r16) * 64 + 32 + quad * 8);
    f32x4 C[4];
#pragma unroll
    for (int jt = 0; jt < 4; ++jt) {
      f32x4 z = {0.f, 0.f, 0.f, 0.f};
      z = __builtin_amdgcn_mfma_f32_16x16x32_bf16(Af0, Bf[0][jt], z, 0, 0, 0);
      z = __builtin_amdgcn_mfma_f32_16x16x32_bf16(Af1, Bf[1][jt], z, 0, 0, 0);
      C[jt] = z;
    }
    float p0 = 0, p1 = 0, p2 = 0, p3 = 0;
#pragma unroll
    for (int jt = 0; jt < 4; ++jt) {
      p0 += wlv[jt] / (1.0f + expf(-(C[jt][0] + bias[jt])));
      p1 += wlv[jt] / (1.0f + expf(-(C[jt][1] + bias[jt])));
      p2 += wlv[jt] / (1.0f + expf(-(C[jt][2] + bias[jt])));
      p3 += wlv[jt] / (1.0f + expf(-(C[jt][3] + bias[jt])));
    }
#pragma unroll
    for (int m = 1; m < 16; m <<= 1) {        // reduce over the 16 cols/quad
      p0 += __shfl_xor(p0, m, 64);
      p1 += __shfl_xor(p1, m, 64);
      p2 += __shfl_xor(p2, m, 64);
      p3 += __shfl_xor(p3, m, 64);
    }
    float ls = 0.0f;
    if (r16 == 0) {
      float e0 = expf(p0 + bl0), e1 = expf(p1 + bl0);
      float e2 = expf(p2 + bl0), e3 = expf(p3 + bl0);
      int r = n0 + quad * 4;
      expv[r] = e0; expv[r + 1] = e1; expv[r + 2] = e2; expv[r + 3] = e3;
      ls = e0 + e1 + e2 + e3;
    }
    ls += __shfl_xor(ls, 16, 64);
    ls += __shfl_xor(ls, 32, 64);
    lsum += ls;                                // lane 0 holds wave total
  }
  if (lane == 0) atomicAdd(&red_part[(blockIdx.x & 63) << 4], lsum);
}

// scale by 1/sum (each wave reduces the 64 padded partials; L2-hot)
__global__ void k_out(const float* __restrict__ expv, int N,
                      const float* __restrict__ red_part, float* __restrict__ out) {
  int i = blockIdx.x * blockDim.x + threadIdx.x;
  int lane = threadIdx.x & 63;
  float s = red_part[lane << 4];
#pragma unroll
  for (int o = 32; o > 0; o >>= 1) s += __shfl_down(s, o, 64);
  s = __shfl(s, 0, 64);
  if (i < N) out[i] = expv[i] / s;
}

// ---------------------------------------------------------------------------

extern "C" void kernel_launch(void* const* d_in, const int* in_sizes, int n_in,
                              void* d_out, int out_size, void* d_ws, size_t ws_size,
                              hipStream_t stream) {
  const float* x   = (const float*)d_in[0];   // [N,6]
  const int*   edg = (const int*)d_in[1];     // [2,E] int32
  const float* w   = (const float*)d_in[2];   // [E]
  const float* W1  = (const float*)d_in[3];   // [6,64]
  const float* b1  = (const float*)d_in[4];
  const float* W2  = (const float*)d_in[5];   // [64,64]
  const float* b2  = (const float*)d_in[6];
  const float* W3  = (const float*)d_in[7];
  const float* b3  = (const float*)d_in[8];
  const float* Wl  = (const float*)d_in[9];   // [64,1]
  const float* bl  = (const float*)d_in[10];
  float* out = (float*)d_out;

  const int N = in_sizes[0] / 6;
  const int E = in_sizes[2];
  const int* row = edg;
  const int* col = edg + E;
  const int NB = (N + 255) >> 8;              // active buckets (196)
  const int NS = (N + 15) / 16;               // MFMA strips (3125)

  // ---- workspace layout ----
  size_t off = 0;
  char* base = (char*)d_ws;
  auto alloc = [&](size_t bytes) -> void* {
    void* p = base + off;
    off += (bytes + 255) & ~(size_t)255;
    return p;
  };
  int*   bfill    = (int*)alloc((size_t)SKB * 16 * 4);   // padded counters (zeroed)
  float* red_part = (float*)alloc((size_t)64 * 16 * 4);  // padded partials (zeroed)
  size_t zero_bytes = off;
  int*   cnt    = (int*)alloc((size_t)N * 4);
  int*   start  = (int*)alloc((size_t)N * 4);
  float* dis    = (float*)alloc((size_t)N * 4);
  float* x8p    = (float*)alloc((size_t)N * 8 * 4);
  float* expv   = (float*)alloc((size_t)N * 4);
  unsigned short* hb  = (unsigned short*)alloc((size_t)N * 64 * 2);  // bf16 h'
  unsigned short* W2b = (unsigned short*)alloc(4096 * 2);
  unsigned short* W3b = (unsigned short*)alloc(4096 * 2);
  // packed CSR (uint32/edge) + shared block (bucket staging, then bf16 agg)
  size_t remain = (ws_size > off) ? (ws_size - off) : 0;
  size_t aggsz = (size_t)N * 64 * 2;
  long long capn = ((long long)remain) / ((long long)NB * 12);
  int CAP = (int)capn;
  if (CAP > 9216) CAP = 9216;
  if (CAP < 8704) CAP = 8704;                 // mean 8163 + ~6 sigma floor
  unsigned* csr = (unsigned*)alloc((size_t)NB * CAP * 4);
  size_t bksz = (size_t)NB * CAP * 8;
  void* shared_blk = alloc(aggsz > bksz ? aggsz : bksz);
  int2*           bucket = (int2*)shared_blk;           // dead after k_build
  unsigned short* aggb   = (unsigned short*)shared_blk; // bf16 agg buffer

  const int gE  = (E + CHUNK - 1) / CHUNK;
  const int gN  = (N + BLK - 1) / BLK;
  const int gN8 = (N * 8 + BLK - 1) / BLK;    // 8 threads per node
  const int gM  = 200;                        // MFMA dense grid (800 waves)

  hipMemsetAsync(d_ws, 0, zero_bytes, stream);

  // CSR build + weight prep
  k_wprep     <<<16, BLK, 0, stream>>>(W2, W3, W2b, W3b);
  k_binscatter<<<gE, BLK, 0, stream>>>(row, col, w, E, bfill, bucket, CAP);
  k_build     <<<NB, BLK, 0, stream>>>(bucket, bfill, x, csr, cnt, start, dis, x8p, CAP, N);

  // layer 1 (fused agg + dense + sigmoid) -> hb (bf16)
  k_layer1<<<gN, BLK, 0, stream>>>(x8p, start, cnt, csr, dis, W1, b1, hb, N);

  // layer 2: agg (bf16 gather -> bf16 agg) ; MFMA dense -> hb (bf16)
  k_agg64      <<<gN8, BLK, 0, stream>>>(hb, start, cnt, csr, dis, aggb, N);
  k_dense64_mfma<<<gM, BLK, 0, stream>>>(aggb, W2b, b2, dis, hb, NS);

  // layer 3: agg ; MFMA dense fused with logits head + exp + partial sums
  k_agg64    <<<gN8, BLK, 0, stream>>>(hb, start, cnt, csr, dis, aggb, N);
  k_head_mfma<<<gM, BLK, 0, stream>>>(aggb, W3b, b3, Wl, bl, expv, red_part, NS);

  // normalize
  k_out<<<gN, BLK, 0, stream>>>(expv, N, red_part, out);
}